// Round 1
// baseline (164.381 us; speedup 1.0000x reference)
//
#include <hip/hip_runtime.h>

#define NHID 25
#define NSTEP 20
#define DD 27            // NHID + 2
#define DT_ (1.0/60.0)
#define EPS_ 1e-4
#define PQ_ 5.0
#define QV_ 200.0
#define QA_ 1.0

// ---------------------------------------------------------------------------
// Setup kernel: one block, computes G [DD x NSTEP] (row-major, float) into ws.
// All math in f64 in LDS. out = x0 @ G afterwards.
// Derivation:
//   s_k = A^k B0;  Tsel[k] = (A^{k+1})[NHID,:]
//   pfin[d][c] = sum_{r>=c} w_r * ((A^{r+1})^T Q0f s_{r-c})[d],  w_r = (r==NS-1?PQ:1)
//   Qf[c1][c2] = 2*(QA*I + sum_{r>=max} w_r * s_{r-c1}^T Q0f s_{r-c2}) + EPS*I
//   W = -2 * pfin @ Qf^{-1}
//   G[d][k] = Tsel[k][d] + sum_{c<=k} W[d][c] * s_{k-c}[NHID]
// ---------------------------------------------------------------------------
__global__ __launch_bounds__(256) void setup_kernel(
    const float* __restrict__ Af, const float* __restrict__ Lq,
    float* __restrict__ G)
{
    __shared__ double A0[DD*DD];
    __shared__ double Pb[2][DD*DD];
    __shared__ double Q0f[DD*DD];
    __shared__ double sv[NSTEP][DD];
    __shared__ double qv[NSTEP][DD];     // qv[k] = Q0f @ s_k
    __shared__ double Hm[NSTEP][NSTEP];
    __shared__ double Qf[NSTEP][NSTEP];
    __shared__ double aug[NSTEP][2*NSTEP];
    __shared__ double prow[2*NSTEP];
    __shared__ double colv[NSTEP];
    __shared__ double pfin[DD][NSTEP];
    __shared__ double Tsel[NSTEP][DD];
    __shared__ double Wm[DD][NSTEP];

    const int t = threadIdx.x;
    const double hdt2 = 0.5 * DT_ * DT_;

    // A0, Q0f, P_0 = I
    for (int i = t; i < DD*DD; i += 256) {
        int r = i / DD, c = i % DD;
        double a;
        if (r < NHID)       a = (c == r) ? 1.0 : ((c == DD-1) ? (double)Af[r] : 0.0);
        else if (r == NHID) a = (c == NHID) ? 1.0 : ((c == DD-1) ? DT_ : 0.0);
        else                a = (c == DD-1) ? 1.0 : 0.0;
        A0[i] = a;
        double qq = 0.0;
        if (r < NHID && c < NHID) {
            double acc = 0.0;
            int km = r < c ? r : c;            // Lq is lower-triangular
            for (int k = 0; k <= km; ++k)
                acc += (double)Lq[r*NHID+k] * (double)Lq[c*NHID+k];
            if (r == c) acc += EPS_;
            qq = acc;
        } else if (r == DD-1 && c == DD-1) qq = QV_;
        Q0f[i] = qq;
        Pb[0][i] = (r == c) ? 1.0 : 0.0;
    }
    for (int i = t; i < DD*NSTEP; i += 256) (&pfin[0][0])[i] = 0.0;
    // s_0 = B0, q_0 = Q0f @ B0  (needs Q0f — but only rows we write here use
    // Q0f entries written by... must sync first)
    __syncthreads();
    if (t < DD) {
        sv[0][t] = (t == NHID) ? hdt2 : ((t == DD-1) ? DT_ : 0.0);
        qv[0][t] = Q0f[t*DD + NHID] * hdt2 + Q0f[t*DD + DD-1] * DT_;
    }
    __syncthreads();

    // Power loop: P_k = P_{k-1} @ A0 ; per step emit s_k, q_k, Tsel[k-1],
    // and accumulate pfin terms for r = k-1.
    int cur = 0;
    for (int k = 1; k <= NSTEP; ++k) {
        int nxt = cur ^ 1;
        for (int i = t; i < DD*DD; i += 256) {
            int r = i / DD, c = i % DD;
            double acc = 0.0;
            for (int m = 0; m < DD; ++m)
                acc += Pb[cur][r*DD+m] * A0[m*DD+c];
            Pb[nxt][i] = acc;
        }
        __syncthreads();
        cur = nxt;
        if (t < DD) {
            Tsel[k-1][t] = Pb[cur][NHID*DD + t];
            if (k < NSTEP)
                sv[k][t] = Pb[cur][t*DD + NHID] * hdt2 + Pb[cur][t*DD + DD-1] * DT_;
        } else if (t >= 32 && t < 32 + DD && k < NSTEP) {
            int d = t - 32;
            double acc = 0.0;
            for (int m = 0; m < DD; ++m)
                acc += Q0f[d*DD+m] *
                       (Pb[cur][m*DD + NHID] * hdt2 + Pb[cur][m*DD + DD-1] * DT_);
            qv[k][d] = acc;
        }
        {   // pfin[:,c] += w_r * P_k^T * qv[r-c],  r = k-1, c = 0..r
            int r = k - 1;
            double w = (r == NSTEP-1) ? PQ_ : 1.0;
            for (int i = t; i < k*DD; i += 256) {
                int c = i / DD, d = i % DD;
                double acc = 0.0;
                for (int m = 0; m < DD; ++m)
                    acc += Pb[cur][m*DD + d] * qv[r-c][m];
                pfin[d][c] += w * acc;
            }
        }
        __syncthreads();
    }

    // H[a][b] = s_a . q_b
    for (int i = t; i < NSTEP*NSTEP; i += 256) {
        int a = i / NSTEP, b = i % NSTEP;
        double acc = 0.0;
        for (int m = 0; m < DD; ++m) acc += sv[a][m] * qv[b][m];
        Hm[a][b] = acc;
    }
    __syncthreads();
    // Q_final
    for (int i = t; i < NSTEP*NSTEP; i += 256) {
        int c1 = i / NSTEP, c2 = i % NSTEP;
        int m0 = c1 > c2 ? c1 : c2;
        double acc = 0.0;
        for (int r = m0; r < NSTEP; ++r)
            acc += ((r == NSTEP-1) ? PQ_ : 1.0) * Hm[r-c1][r-c2];
        Qf[c1][c2] = 2.0 * (acc + ((c1 == c2) ? QA_ : 0.0)) + ((c1 == c2) ? EPS_ : 0.0);
    }
    __syncthreads();
    // Gauss-Jordan inverse (SPD, no pivoting)
    for (int i = t; i < NSTEP*2*NSTEP; i += 256) {
        int r = i / (2*NSTEP), c = i % (2*NSTEP);
        aug[r][c] = (c < NSTEP) ? Qf[r][c] : ((c - NSTEP == r) ? 1.0 : 0.0);
    }
    __syncthreads();
    for (int piv = 0; piv < NSTEP; ++piv) {
        if (t < 2*NSTEP)       prow[t] = aug[piv][t];
        else if (t < 3*NSTEP)  colv[t - 2*NSTEP] = aug[t - 2*NSTEP][piv];
        __syncthreads();
        double pinvv = 1.0 / prow[piv];
        for (int i = t; i < NSTEP*2*NSTEP; i += 256) {
            int r = i / (2*NSTEP), c = i % (2*NSTEP);
            if (r == piv) aug[r][c] = prow[c] * pinvv;
            else          aug[r][c] -= colv[r] * pinvv * prow[c];
        }
        __syncthreads();
    }
    // W = -2 * pfin @ Qinv
    for (int i = t; i < DD*NSTEP; i += 256) {
        int d = i / NSTEP, c = i % NSTEP;
        double acc = 0.0;
        for (int j = 0; j < NSTEP; ++j) acc += pfin[d][j] * aug[j][NSTEP + c];
        Wm[d][c] = -2.0 * acc;
    }
    __syncthreads();
    // G[d][k] = Tsel[k][d] + sum_{c<=k} W[d][c] * s_{k-c}[NHID]
    for (int i = t; i < DD*NSTEP; i += 256) {
        int d = i / NSTEP, kk = i % NSTEP;
        double acc = Tsel[kk][d];
        for (int c = 0; c <= kk; ++c) acc += Wm[d][c] * sv[kk-c][NHID];
        G[i] = (float)acc;
    }
}

// ---------------------------------------------------------------------------
// Main kernel: out[b,:] = x0[b,:] @ G, x0 = [x | gp | gv]. One thread per row.
// 256 rows/block: coalesced float4 staging of x into LDS, G broadcast from LDS
// (float2-vectorized), direct float4 stores of the 20-float output row.
// ---------------------------------------------------------------------------
__global__ __launch_bounds__(256) void mpc_main(
    const float* __restrict__ x, const float* __restrict__ gp,
    const float* __restrict__ gv, const float* __restrict__ G,
    float* __restrict__ out)
{
    __shared__ float xs[256 * NHID];      // 6400 floats
    __shared__ float Gs[DD * NSTEP];      // 540 floats
    const int t = threadIdx.x;
    const size_t b0 = (size_t)blockIdx.x * 256;

    for (int i = t; i < DD*NSTEP; i += 256) Gs[i] = G[i];
    {
        const float4* xsrc = (const float4*)(x + b0 * NHID);
        float4* xdst = (float4*)xs;
        #pragma unroll
        for (int i = 0; i < 7; ++i) {
            int idx = t + 256 * i;
            if (idx < 1600) xdst[idx] = xsrc[idx];
        }
    }
    const float p = gp[b0 + t];
    const float v = gv[b0 + t];
    __syncthreads();

    const float2* G2 = (const float2*)Gs;
    float2 acc[10];
    #pragma unroll
    for (int kk = 0; kk < 10; ++kk) {
        float2 gpp = G2[NHID*10 + kk];
        float2 gvv = G2[(NHID+1)*10 + kk];
        acc[kk].x = p * gpp.x + v * gvv.x;
        acc[kk].y = p * gpp.y + v * gvv.y;
    }
    const float* xr = xs + t * NHID;
    #pragma unroll
    for (int i = 0; i < NHID; ++i) {
        float xi = xr[i];
        #pragma unroll
        for (int kk = 0; kk < 10; ++kk) {
            float2 g = G2[i*10 + kk];
            acc[kk].x = fmaf(xi, g.x, acc[kk].x);
            acc[kk].y = fmaf(xi, g.y, acc[kk].y);
        }
    }
    float4* o4 = (float4*)(out + (b0 + t) * NSTEP);
    #pragma unroll
    for (int q = 0; q < 5; ++q)
        o4[q] = make_float4(acc[2*q].x, acc[2*q].y, acc[2*q+1].x, acc[2*q+1].y);
}

extern "C" void kernel_launch(void* const* d_in, const int* in_sizes, int n_in,
                              void* d_out, int out_size, void* d_ws, size_t ws_size,
                              hipStream_t stream) {
    const float* x  = (const float*)d_in[0];
    const float* gp = (const float*)d_in[1];
    const float* gv = (const float*)d_in[2];
    const float* Af = (const float*)d_in[3];
    const float* Lq = (const float*)d_in[4];
    float* out = (float*)d_out;
    float* G   = (float*)d_ws;            // 540 floats of scratch

    const int B = in_sizes[1];            // gripper_p element count = BATCH
    hipLaunchKernelGGL(setup_kernel, dim3(1), dim3(256), 0, stream, Af, Lq, G);
    hipLaunchKernelGGL(mpc_main, dim3(B / 256), dim3(256), 0, stream,
                       x, gp, gv, G, out);
}

// Round 2
// 108.545 us; speedup vs baseline: 1.5144x; 1.5144x over previous
//
#include <hip/hip_runtime.h>

#define NHID 25
#define NSTEP 20
#define DT_ (1.0/60.0)
#define EPS_ 1e-4
#define PQ_ 5.0
#define QV_ 200.0
#define QA_ 1.0

// ---------------------------------------------------------------------------
// Closed-form reduction (verified against the R0 full-matrix kernel's math):
//   A0^k = [[I, 0, k*Af],[0, [[1,k*dt],[0,1]]]]
//   s_k  = A0^k B0 = [k*dt*Af ; hdt2 + k*dt^2 ; dt]
//   Tsel[k] (row NH of A0^{k+1}) = [0..0, 1, (k+1)*dt]
//   u = Q0*Af,  alpha = Af^T Q0 Af
//   Qf[c1][c2] = (2QA+EPS)*delta + 2dt^2 * sum_{r>=max} w_r((r-c1)(r-c2)alpha + QV)
//   phi[c] = sum_{r>=c} w_r (r-c)
//   rho[c] = sum_{r>=c} w_r ((r+1)(r-c)alpha + QV)
//   z1 = Qf^{-1} phi, z2 = Qf^{-1} rho
//   bvec[k] = -2dt * sum_{c<=k} z1[c]*(hdt2+(k-c)dt^2)
//   gvec[k] = (k+1)dt - 2dt * sum_{c<=k} z2[c]*(hdt2+(k-c)dt^2)
//   out[b,k] = gp_b + (x_b . u) * bvec[k] + gv_b * gvec[k]
// Setup runs in ONE 64-lane wave: s_barrier with a single resident wave is
// ~free, and all loops are <= 20-27 iterations of f64 VALU.
// C layout (float): [0..24]=u, [32..51]=bvec, [64..83]=gvec.
// ---------------------------------------------------------------------------
__global__ __launch_bounds__(64) void setup_kernel(
    const float* __restrict__ Af, const float* __restrict__ Lq,
    float* __restrict__ C)
{
    __shared__ double w[NHID];
    __shared__ double u[NHID];
    __shared__ double alpha_s;
    __shared__ double aug[NSTEP][NSTEP + 2];   // [Qf | phi | rho]
    __shared__ double prow[NSTEP + 2];
    __shared__ double colv[NSTEP];

    const int t = threadIdx.x;
    const double dt = DT_;

    // w = Lq^T Af   (Lq lower-triangular)
    if (t < NHID) {
        double acc = 0.0;
        for (int i = t; i < NHID; ++i)
            acc += (double)Lq[i * NHID + t] * (double)Af[i];
        w[t] = acc;
    }
    __syncthreads();
    // u = Lq w + EPS*Af
    if (t < NHID) {
        double acc = EPS_ * (double)Af[t];
        for (int j = 0; j <= t; ++j)
            acc += (double)Lq[t * NHID + j] * w[j];
        u[t] = acc;
    }
    __syncthreads();
    if (t == 0) {
        double a = 0.0;
        for (int i = 0; i < NHID; ++i) a += (double)Af[i] * u[i];
        alpha_s = a;
    }
    __syncthreads();
    const double alpha = alpha_s;

    // Build augmented system [Qf | phi | rho], all closed form.
    for (int idx = t; idx < NSTEP * (NSTEP + 2); idx += 64) {
        int r = idx / (NSTEP + 2), c = idx % (NSTEP + 2);
        double val;
        if (c < NSTEP) {
            int m0 = r > c ? r : c;
            double s = 0.0;
            for (int rr = m0; rr < NSTEP; ++rr) {
                double wr = (rr == NSTEP - 1) ? PQ_ : 1.0;
                s += wr * ((double)(rr - r) * (double)(rr - c) * alpha + QV_);
            }
            val = 2.0 * dt * dt * s + ((r == c) ? (2.0 * QA_ + EPS_) : 0.0);
        } else if (c == NSTEP) {          // phi
            double s = 0.0;
            for (int rr = r; rr < NSTEP; ++rr)
                s += ((rr == NSTEP - 1) ? PQ_ : 1.0) * (double)(rr - r);
            val = s;
        } else {                          // rho
            double s = 0.0;
            for (int rr = r; rr < NSTEP; ++rr)
                s += ((rr == NSTEP - 1) ? PQ_ : 1.0) *
                     ((double)(rr + 1) * (double)(rr - r) * alpha + QV_);
            val = s;
        }
        aug[r][c] = val;
    }
    __syncthreads();

    // Gauss-Jordan (SPD, no pivoting). 20 pivots, 2 cheap single-wave barriers each.
    for (int piv = 0; piv < NSTEP; ++piv) {
        if (t < NSTEP + 2)               prow[t] = aug[piv][t];
        else if (t >= 32 && t < 32 + NSTEP) colv[t - 32] = aug[t - 32][piv];
        __syncthreads();
        double pinv = 1.0 / prow[piv];
        for (int idx = t; idx < NSTEP * (NSTEP + 2); idx += 64) {
            int r = idx / (NSTEP + 2), c = idx % (NSTEP + 2);
            if (r == piv) aug[r][c] = prow[c] * pinv;
            else          aug[r][c] -= colv[r] * pinv * prow[c];
        }
        __syncthreads();
    }

    // Emit coefficients.
    if (t < NHID) C[t] = (float)u[t];
    if (t < NSTEP) {
        const double hdt2 = 0.5 * dt * dt;
        double b = 0.0, g = 0.0;
        for (int c = 0; c <= t; ++c) {
            double ssel = hdt2 + (double)(t - c) * dt * dt;
            b += aug[c][NSTEP]     * ssel;   // z1[c]
            g += aug[c][NSTEP + 1] * ssel;   // z2[c]
        }
        C[32 + t] = (float)(-2.0 * dt * b);
        C[64 + t] = (float)((double)(t + 1) * dt - 2.0 * dt * g);
    }
}

// ---------------------------------------------------------------------------
// Main kernel: out[b,k] = gp + t_b*bvec[k] + gv*gvec[k], t_b = x_b . u.
// 256 rows/block; coalesced float4 LDS staging of x; float4 stores.
// ---------------------------------------------------------------------------
__global__ __launch_bounds__(256) void mpc_main(
    const float* __restrict__ x, const float* __restrict__ gp,
    const float* __restrict__ gv, const float* __restrict__ C,
    float* __restrict__ out)
{
    __shared__ float xs[256 * NHID];     // 6400 floats
    __shared__ float us[NHID];
    __shared__ float bs[NSTEP];
    __shared__ float gs[NSTEP];
    const int t = threadIdx.x;
    const size_t b0 = (size_t)blockIdx.x * 256;

    if (t < NHID)                us[t] = C[t];
    else if (t >= 32 && t < 52)  bs[t - 32] = C[t];
    else if (t >= 64 && t < 84)  gs[t - 64] = C[t];

    {
        const float4* xsrc = (const float4*)(x + b0 * NHID);
        float4* xdst = (float4*)xs;
        #pragma unroll
        for (int i = 0; i < 7; ++i) {
            int idx = t + 256 * i;
            if (idx < 1600) xdst[idx] = xsrc[idx];
        }
    }
    const float p = gp[b0 + t];
    const float v = gv[b0 + t];
    __syncthreads();

    const float* xr = xs + t * NHID;
    float tb = 0.0f;
    #pragma unroll
    for (int i = 0; i < NHID; ++i)
        tb = fmaf(xr[i], us[i], tb);

    float4* o4 = (float4*)(out + (b0 + t) * NSTEP);
    #pragma unroll
    for (int q = 0; q < 5; ++q) {
        float4 r;
        r.x = fmaf(tb, bs[4*q+0], fmaf(v, gs[4*q+0], p));
        r.y = fmaf(tb, bs[4*q+1], fmaf(v, gs[4*q+1], p));
        r.z = fmaf(tb, bs[4*q+2], fmaf(v, gs[4*q+2], p));
        r.w = fmaf(tb, bs[4*q+3], fmaf(v, gs[4*q+3], p));
        o4[q] = r;
    }
}

extern "C" void kernel_launch(void* const* d_in, const int* in_sizes, int n_in,
                              void* d_out, int out_size, void* d_ws, size_t ws_size,
                              hipStream_t stream) {
    const float* x  = (const float*)d_in[0];
    const float* gp = (const float*)d_in[1];
    const float* gv = (const float*)d_in[2];
    const float* Af = (const float*)d_in[3];
    const float* Lq = (const float*)d_in[4];
    float* out = (float*)d_out;
    float* C   = (float*)d_ws;            // 96 floats of scratch

    const int B = in_sizes[1];            // BATCH
    hipLaunchKernelGGL(setup_kernel, dim3(1), dim3(64), 0, stream, Af, Lq, C);
    hipLaunchKernelGGL(mpc_main, dim3(B / 256), dim3(256), 0, stream,
                       x, gp, gv, C, out);
}

// Round 3
// 94.507 us; speedup vs baseline: 1.7394x; 1.1485x over previous
//
#include <hip/hip_runtime.h>

#define NHID 25
#define NSTEP 20
#define DT_ (1.0/60.0)
#define EPS_ 1e-4
#define PQ_ 5.0
#define QV_ 200.0
#define QA_ 1.0

// ---------------------------------------------------------------------------
// Fully fused: every block's wave 0 recomputes the 96 setup coefficients
// (register Gauss-Jordan, shuffle broadcasts, zero barriers inside), while
// the block stages its 256 x-rows. Closed forms (HW-verified in R2):
//   u = Q0*Af, alpha = Af^T Q0 Af
//   Qf[r][c] = (2QA+EPS)delta + 2dt^2 sum_{rr>=max} w_rr((rr-r)(rr-c)alpha+QV)
//   phi[r] = sum_{rr>=r} w_rr (rr-r)
//   rho[r] = sum_{rr>=r} w_rr ((rr+1)(rr-r)alpha + QV)
//   [z1 z2] = Qf^{-1} [phi rho]
//   bvec[k] = -2dt sum_{c<=k} z1[c](hdt2+(k-c)dt^2)
//   gvec[k] = (k+1)dt - 2dt sum_{c<=k} z2[c](hdt2+(k-c)dt^2)
//   out[b,k] = gp_b + (x_b . u)*bvec[k] + gv_b*gvec[k]
// ---------------------------------------------------------------------------
__global__ __launch_bounds__(256, 2) void mpc_fused(
    const float* __restrict__ x, const float* __restrict__ gp,
    const float* __restrict__ gv, const float* __restrict__ Af,
    const float* __restrict__ Lq, float* __restrict__ out)
{
    __shared__ float xs[256 * NHID];      // 25600 B
    __shared__ float Lqs[NHID * NHID];    // 2500 B
    __shared__ float us[NHID];
    __shared__ float bs[NSTEP];
    __shared__ float gs[NSTEP];

    const int t = threadIdx.x;
    const size_t b0 = (size_t)blockIdx.x * 256;

    // ---- issue all global loads up-front ----
    double af = 0.0;
    if (t < NHID) af = (double)Af[t];                 // wave-0 lanes only use it
    for (int i = t; i < NHID * NHID; i += 256) Lqs[i] = Lq[i];
    {
        const float4* xsrc = (const float4*)(x + b0 * NHID);
        float4* xdst = (float4*)xs;
        #pragma unroll
        for (int i = 0; i < 7; ++i) {
            int idx = t + 256 * i;
            if (idx < 1600) xdst[idx] = xsrc[idx];    // 6400 floats = 1600 float4
        }
    }
    const float p = gp[b0 + t];
    const float v = gv[b0 + t];
    __syncthreads();

    if (t < 64) {   // wave 0 only: register setup, shuffles, no barriers
        const double dt = DT_;
        const int tr = (t < NHID) ? t : 0;            // clamp LDS indices

        // Phase A: w = Lq^T Af, u = Lq w + eps Af, alpha = Af . u
        double wv = 0.0;
        #pragma unroll
        for (int i = 0; i < NHID; ++i) {
            double afi = __shfl(af, i, 64);
            if (i >= t && t < NHID) wv += (double)Lqs[i * NHID + tr] * afi;
        }
        double uv = EPS_ * af;
        #pragma unroll
        for (int j = 0; j < NHID; ++j) {
            double wj = __shfl(wv, j, 64);
            if (j <= t && t < NHID) uv += (double)Lqs[tr * NHID + j] * wj;
        }
        double av = af * uv;                          // 0 for lanes >= NHID
        #pragma unroll
        for (int off = 32; off >= 1; off >>= 1)
            av += __shfl_xor(av, off, 64);
        const double alpha = av;

        // Phase B: lane r (=t<20) builds row [Qf[r][*] | phi[r] | rho[r]]
        double row[NSTEP + 2];
        #pragma unroll
        for (int c = 0; c < NSTEP; ++c) {
            int m0 = (t > c) ? t : c;                 // t>=20 -> empty loop -> 0
            double s = 0.0;
            for (int rr = m0; rr < NSTEP; ++rr) {
                double wr = (rr == NSTEP - 1) ? PQ_ : 1.0;
                s += wr * ((double)(rr - t) * (double)(rr - c) * alpha + QV_);
            }
            row[c] = 2.0 * dt * dt * s + ((t == c) ? (2.0 * QA_ + EPS_) : 0.0);
        }
        {
            double s20 = 0.0, s21 = 0.0;
            for (int rr = t; rr < NSTEP; ++rr) {
                double wr = (rr == NSTEP - 1) ? PQ_ : 1.0;
                s20 += wr * (double)(rr - t);
                s21 += wr * ((double)(rr + 1) * (double)(rr - t) * alpha + QV_);
            }
            row[NSTEP]     = s20;
            row[NSTEP + 1] = s21;
        }

        // Gauss-Jordan, fully unrolled (static register indexing), SPD no-pivot.
        #pragma unroll
        for (int piv = 0; piv < NSTEP; ++piv) {
            double pr[NSTEP + 2];
            #pragma unroll
            for (int c = piv; c < NSTEP + 2; ++c)
                pr[c] = __shfl(row[c], piv, 64);
            double pinv = 1.0 / pr[piv];
            double f = row[piv] * pinv;               // lanes>=20: row==0 -> f==0
            #pragma unroll
            for (int c = piv; c < NSTEP + 2; ++c) {
                double nv = row[c] - f * pr[c];
                row[c] = (t == piv) ? (pr[c] * pinv) : nv;
            }
        }
        double z1 = row[NSTEP], z2 = row[NSTEP + 1];  // lane r holds z[r]

        // Phase C: prefix-weighted combos -> bvec, gvec
        const double hdt2 = 0.5 * dt * dt;
        double bacc = 0.0, gacc = 0.0;
        #pragma unroll
        for (int c = 0; c < NSTEP; ++c) {
            double z1c = __shfl(z1, c, 64);
            double z2c = __shfl(z2, c, 64);
            if (c <= t) {
                double ssel = hdt2 + (double)(t - c) * dt * dt;
                bacc += z1c * ssel;
                gacc += z2c * ssel;
            }
        }
        if (t < NHID) us[t] = (float)uv;
        if (t < NSTEP) {
            bs[t] = (float)(-2.0 * dt * bacc);
            gs[t] = (float)((double)(t + 1) * dt - 2.0 * dt * gacc);
        }
    }
    __syncthreads();

    // ---- batch compute: out[b,k] = p + tb*bs[k] + v*gs[k] ----
    const float* xr = xs + t * NHID;
    float tb = 0.0f;
    #pragma unroll
    for (int i = 0; i < NHID; ++i)
        tb = fmaf(xr[i], us[i], tb);

    float4* o4 = (float4*)(out + (b0 + t) * NSTEP);
    #pragma unroll
    for (int q = 0; q < 5; ++q) {
        float4 r;
        r.x = fmaf(tb, bs[4*q+0], fmaf(v, gs[4*q+0], p));
        r.y = fmaf(tb, bs[4*q+1], fmaf(v, gs[4*q+1], p));
        r.z = fmaf(tb, bs[4*q+2], fmaf(v, gs[4*q+2], p));
        r.w = fmaf(tb, bs[4*q+3], fmaf(v, gs[4*q+3], p));
        o4[q] = r;
    }
}

extern "C" void kernel_launch(void* const* d_in, const int* in_sizes, int n_in,
                              void* d_out, int out_size, void* d_ws, size_t ws_size,
                              hipStream_t stream) {
    const float* x  = (const float*)d_in[0];
    const float* gp = (const float*)d_in[1];
    const float* gv = (const float*)d_in[2];
    const float* Af = (const float*)d_in[3];
    const float* Lq = (const float*)d_in[4];
    float* out = (float*)d_out;

    const int B = in_sizes[1];            // BATCH
    hipLaunchKernelGGL(mpc_fused, dim3(B / 256), dim3(256), 0, stream,
                       x, gp, gv, Af, Lq, out);
}